// Round 4
// baseline (158.319 us; speedup 1.0000x reference)
//
#include <hip/hip_runtime.h>
#include <hip/hip_bf16.h>
#include <stdint.h>

#define Ssz 1024
#define Bsz 4
#define Csz 1024
#define Hsz 16
#define Msz 4096   // S*B

typedef unsigned short u16;
typedef __attribute__((ext_vector_type(8))) short bf16x8;
typedef __attribute__((ext_vector_type(8))) unsigned short u16x8;
typedef __attribute__((ext_vector_type(4))) float f32x4;
typedef __attribute__((ext_vector_type(4))) unsigned short u16x4;

__device__ __forceinline__ u16 f2bf(float f) {
  union { float f; unsigned u; } x; x.f = f;
  unsigned r = x.u + 0x7fffu + ((x.u >> 16) & 1u);   // RNE
  return (u16)(r >> 16);
}

__device__ __forceinline__ void glds16(const void* g, void* l) {
  __builtin_amdgcn_global_load_lds(
      (__attribute__((address_space(1))) void*)g,
      (__attribute__((address_space(3))) void*)l, 16, 0, 0);
}

// XOR-swizzle a logical LDS byte offset (bank-spread for 256B-strided rows)
__device__ __forceinline__ int swzb(int x) { return x ^ (((x >> 8) & 7) << 4); }

// ---------------- convert weights -> Bq, B2 ; biasK ; uwke/vwke (fused prep1) ----------------
// block = one row c. threads cover 1024 channels (4 each).
__global__ __launch_bounds__(256) void k_convert_w(
    const float* __restrict__ Wq, const float* __restrict__ Wke, const float* __restrict__ Wkr,
    const float* __restrict__ bke, const float* __restrict__ bkr,
    const float* __restrict__ uu, const float* __restrict__ vv,
    u16* __restrict__ Bq, u16* __restrict__ B2, float* __restrict__ biasK,
    float* __restrict__ uwke, float* __restrict__ vwke) {
  int c = blockIdx.x;
  int tid = threadIdx.x;
  int c4 = tid * 4;
  float4 q = *(const float4*)(Wq + (size_t)c * Csz + c4);
  float4 e = *(const float4*)(Wke + (size_t)c * Csz + c4);
  float4 k = *(const float4*)(Wkr + (size_t)c * Csz + c4);
  u16x4 qo = { f2bf(q.x), f2bf(q.y), f2bf(q.z), f2bf(q.w) };
  u16x4 eo = { f2bf(e.x), f2bf(e.y), f2bf(e.z), f2bf(e.w) };
  u16x4 ko = { f2bf(k.x), f2bf(k.y), f2bf(k.z), f2bf(k.w) };
  *(u16x4*)(Bq + (size_t)c * 1024 + c4) = qo;
  *(u16x4*)(B2 + (size_t)c * 2048 + c4) = eo;
  *(u16x4*)(B2 + (size_t)c * 2048 + 1024 + c4) = ko;
  // fused prep1: uwke[c] = Wke[c]·u + bke[c], vwke[c] = Wkr[c]·v + bkr[c]
  float4 u4 = *(const float4*)(uu + c4);
  float4 v4 = *(const float4*)(vv + c4);
  float se = e.x * u4.x + e.y * u4.y + e.z * u4.z + e.w * u4.w;
  float sk = k.x * v4.x + k.y * v4.y + k.z * v4.z + k.w * v4.w;
  for (int m = 32; m; m >>= 1) { se += __shfl_xor(se, m); sk += __shfl_xor(sk, m); }
  __shared__ float red[2][4];
  if ((tid & 63) == 0) { red[0][tid >> 6] = se; red[1][tid >> 6] = sk; }
  __syncthreads();
  if (tid == 0) {
    uwke[c] = red[0][0] + red[0][1] + red[0][2] + red[0][3] + bke[c];
    vwke[c] = red[1][0] + red[1][1] + red[1][2] + red[1][3] + bkr[c];
    biasK[c] = bke[c] + bkr[c];
  }
}

// ---------------- prep 2: wu = Wke^T uwke ; wv = Wkr^T vwke ; cst ----------------
__global__ __launch_bounds__(256) void k_prep2(
    const float* __restrict__ Wke, const float* __restrict__ Wkr,
    const float* __restrict__ uwke, const float* __restrict__ vwke,
    const float* __restrict__ bke, const float* __restrict__ bkr,
    float* __restrict__ wu, float* __restrict__ wv, float* __restrict__ cst) {
  int bid = blockIdx.x;
  int tid = threadIdx.x;
  if (bid < 64) {
    const float* W = (bid < 32) ? Wke : Wkr;
    const float* sv = (bid < 32) ? uwke : vwke;
    float* o = (bid < 32) ? wu : wv;
    int d = (bid & 31) * 32 + (tid & 31);
    int cpar = tid >> 5;                    // 0..7
    float acc = 0.f;
    #pragma unroll 8
    for (int c = cpar; c < Csz; c += 8) acc += sv[c] * W[(size_t)c * Csz + d];
    __shared__ float red[8][32];
    red[cpar][tid & 31] = acc;
    __syncthreads();
    if (cpar == 0) {
      float s = 0.f;
      #pragma unroll
      for (int i = 0; i < 8; i++) s += red[i][tid & 31];
      o[d] = s;
    }
  } else {
    float s = 0.f;
    for (int i = tid; i < Csz; i += 256) s += uwke[i] * bke[i] + vwke[i] * bkr[i];
    for (int m = 32; m; m >>= 1) s += __shfl_xor(s, m);
    __shared__ float red1[4];
    if ((tid & 63) == 0) red1[tid >> 6] = s;
    __syncthreads();
    if (tid == 0) cst[0] = red1[0] + red1[1] + red1[2] + red1[3];
  }
}

// ---------------- convert x,r -> A2 bf16 [4096][2048] ; fused biasTB ----------------
// block = one row m = t*4+b.
__global__ __launch_bounds__(256) void k_convert_xr_bias(
    const float* __restrict__ x, const float* __restrict__ r,
    const float* __restrict__ wu, const float* __restrict__ wv,
    const float* __restrict__ cst, u16* __restrict__ A2, float* __restrict__ biasTB) {
  int m = blockIdx.x;
  int tid = threadIdx.x;
  int c4 = tid * 4;
  float4 xv = *(const float4*)(x + (size_t)m * Csz + c4);
  float4 rv = *(const float4*)(r + (size_t)m * Csz + c4);
  u16x4 xo = { f2bf(xv.x), f2bf(xv.y), f2bf(xv.z), f2bf(xv.w) };
  u16x4 ro = { f2bf(rv.x), f2bf(rv.y), f2bf(rv.z), f2bf(rv.w) };
  *(u16x4*)(A2 + (size_t)m * 2048 + c4) = xo;
  *(u16x4*)(A2 + (size_t)m * 2048 + 1024 + c4) = ro;
  // fused bias: biasTB[m] = x[m]·wu + r[m]·wv + cst
  float4 a = *(const float4*)(wu + c4);
  float4 b = *(const float4*)(wv + c4);
  float s = xv.x * a.x + xv.y * a.y + xv.z * a.z + xv.w * a.w
          + rv.x * b.x + rv.y * b.y + rv.z * b.z + rv.w * b.w;
  for (int mm = 32; mm; mm >>= 1) s += __shfl_xor(s, mm);
  __shared__ float red[4];
  if ((tid & 63) == 0) red[tid >> 6] = s;
  __syncthreads();
  if (tid == 0) biasTB[m] = red[0] + red[1] + red[2] + red[3] + cst[0];
}

// ---------------- fused projection GEMMs (z=0: Q, z=1: K) ----------------
// 2-phase double-buffered pipeline: STAGE(t+1) issued before compute(t),
// one barrier per K-step. Output in MFMA-fragment-major layout:
//   OF[((s_tile*4 + b)*16 + head)*2 + kk][lane][e]  (512 u16 = 1KB chunks)
__global__ __launch_bounds__(256) void k_gemm(
    const u16* __restrict__ A2, const u16* __restrict__ Bq, const u16* __restrict__ B2,
    const float* __restrict__ bq, const float* __restrict__ biasK,
    u16* __restrict__ QF, u16* __restrict__ KF) {
  __shared__ u16 As[2][4096];
  __shared__ u16 Bs[2][4096];
  __shared__ u16 ep[4][4096];          // 8KB per-wave transpose staging
  const int z = blockIdx.z;
  const u16* A = A2; const int lda = 2048;
  const u16* B = (z == 0) ? Bq : B2;
  const int ldb = (z == 0) ? 1024 : 2048;
  const float* bias = (z == 0) ? bq : biasK;
  u16* OF = (z == 0) ? QF : KF;
  const int NT = ((z == 0) ? 1024 : 2048) >> 5;

  const int tid = threadIdx.x;
  const int bm = blockIdx.y * 128, bn = blockIdx.x * 128;
  const int wave = tid >> 6, lane = tid & 63;
  const int wm = (wave & 1) * 64, wn = (wave >> 1) * 64;
  const int fr = lane & 15, kg = (lane >> 4) * 8;

  // per-thread staging addresses (2 chunks of A, 2 of B)
  const int ch0 = tid, ch1 = 256 + tid;
  const int r0 = ch0 >> 2, c0 = (ch0 & 3) * 8;
  const int r1 = ch1 >> 2, c1 = (ch1 & 3) * 8;
  const u16* a0 = A + (size_t)(bm + r0) * lda + c0;
  const u16* a1 = A + (size_t)(bm + r1) * lda + c1;
  const u16* b0 = B + (size_t)(bn + r0) * ldb + c0;
  const u16* b1 = B + (size_t)(bn + r1) * ldb + c1;

  f32x4 acc[4][4] = {};

  // prologue: stage tile 0 into buf 0
  glds16(a0, &As[0][ch0 * 8]);  glds16(a1, &As[0][ch1 * 8]);
  glds16(b0, &Bs[0][ch0 * 8]);  glds16(b1, &Bs[0][ch1 * 8]);
  __syncthreads();

  for (int t = 0; t < NT; t++) {
    const int cur = t & 1;
    if (t + 1 < NT) {                  // prefetch next tile into other buffer
      const int kt = (t + 1) * 32;
      glds16(a0 + kt, &As[cur ^ 1][ch0 * 8]);  glds16(a1 + kt, &As[cur ^ 1][ch1 * 8]);
      glds16(b0 + kt, &Bs[cur ^ 1][ch0 * 8]);  glds16(b1 + kt, &Bs[cur ^ 1][ch1 * 8]);
    }
    bf16x8 af[4], bf[4];
    #pragma unroll
    for (int mi = 0; mi < 4; mi++) af[mi] = *(const bf16x8*)(&As[cur][(wm + mi * 16 + fr) * 32 + kg]);
    #pragma unroll
    for (int ni = 0; ni < 4; ni++) bf[ni] = *(const bf16x8*)(&Bs[cur][(wn + ni * 16 + fr) * 32 + kg]);
    #pragma unroll
    for (int mi = 0; mi < 4; mi++)
      #pragma unroll
      for (int ni = 0; ni < 4; ni++)
        acc[mi][ni] = __builtin_amdgcn_mfma_f32_16x16x32_bf16(af[mi], bf[ni], acc[mi][ni], 0, 0, 0);
    __syncthreads();                   // vmcnt(0): prefetch landed; all reads of cur done
  }

  // ---- epilogue: per-wave transpose into fragment layout (see R3 notes)
  const int hi = lane >> 4;
  const int e8 = fr & 7;
  const int fr3 = fr >> 3;
  float bvn[4];
  #pragma unroll
  for (int ni = 0; ni < 4; ni++) bvn[ni] = bias[bn + wn + ni * 16 + fr];
  #pragma unroll
  for (int ni = 0; ni < 4; ni++) {
    const int kk = ni >> 1;
    const int g = (ni * 2 + fr3) & 3;
    #pragma unroll
    for (int mi = 0; mi < 4; mi++) {
      const int inner = (g * 16 + mi * 4 + hi) * 8 + e8;
      #pragma unroll
      for (int j = 0; j < 4; j++)
        ep[wave][(j * 2 + kk) * 512 + inner] = f2bf(acc[mi][ni][j] + bvn[ni]);
    }
  }
  const int s_tile = (bm >> 6) + (wm >> 6);
  const int nh = (bn + wn) >> 6;
  #pragma unroll
  for (int p = 0; p < 8; p++) {
    const int b2 = p >> 1, kk = p & 1;
    u16x8 v = *(const u16x8*)(&ep[wave][p * 512 + lane * 8]);
    size_t ci = ((size_t)(s_tile * 4 + b2) * 16 + nh) * 2 + kk;
    __builtin_nontemporal_store(v, (u16x8*)(OF + ci * 512 + lane * 8));
  }
}

// ---------------- attention ----------------
// out[s,t,b,n] = sum_c Q[s,b,n,c]*K[t,b,n,c] + bias[t,b]
// QF/KF are fragment-major: every operand load = 64 lanes x 16B contiguous.
__global__ __launch_bounds__(256, 3) void k_attn(
    const u16* __restrict__ QF, const u16* __restrict__ KF,
    const float* __restrict__ biasTB, float* __restrict__ out) {
  // XCD-aware 2D partition: xcd -> (sx, tx); t-panels of 8 tiles for L2 residency
  int id = blockIdx.x;                  // 0..4095
  int xcd = id & 7, within = id >> 3;
  int sx = xcd & 3, tx = xcd >> 2;
  int panel = within >> 7;              // 0..3
  int pl = within & 127;
  int s_tile = sx * 16 + (pl >> 3);     // 0..63
  int t_tile = tx * 32 + panel * 8 + (pl & 7);
  int s0 = s_tile * 16, t0 = t_tile * 16;

  int tid = threadIdx.x;
  int wave = tid >> 6, lane = tid & 63; // wave = b
  int fr = lane & 15;

  const u16* qp = QF + (size_t)(s_tile * 4 + wave) * 16384 + lane * 8;  // 16 heads*2kk*512
  const u16* kp = KF + (size_t)(t_tile * 4 + wave) * 16384 + lane * 8;

  f32x4 acc[16];
  #pragma unroll
  for (int n = 0; n < 16; n++) acc[n] = (f32x4){0.f, 0.f, 0.f, 0.f};

  #pragma unroll
  for (int n = 0; n < 16; n++) {
    #pragma unroll
    for (int kk = 0; kk < 2; kk++) {
      bf16x8 a  = *(const bf16x8*)(qp + (n * 2 + kk) * 512);
      bf16x8 bb = *(const bf16x8*)(kp + (n * 2 + kk) * 512);
      acc[n] = __builtin_amdgcn_mfma_f32_16x16x32_bf16(a, bb, acc[n], 0, 0, 0);
    }
  }

  // stage + store: 2 phases of 8 s-rows through LDS [8][16][4][16] f32 (32KB)
  __shared__ float lds[8192];
  float bv = biasTB[(t0 + (tid >> 4)) * 4 + ((tid >> 2) & 3)];
  int hi = (lane >> 4) & 1;
  int myg = (lane >> 4) >> 1;           // this lane's acc rows live in phase myg

  #pragma unroll
  for (int g = 0; g < 2; g++) {
    __syncthreads();
    if (myg == g) {
      #pragma unroll
      for (int j = 0; j < 4; j++) {
        int lbase = (((hi * 4 + j) * 16 + fr) * 4 + wave) * 64;   // logical byte
        #pragma unroll
        for (int n0 = 0; n0 < 16; n0 += 4) {
          f32x4 v = { acc[n0][j], acc[n0 + 1][j], acc[n0 + 2][j], acc[n0 + 3][j] };
          *(f32x4*)((char*)lds + swzb(lbase + n0 * 4)) = v;
        }
      }
    }
    __syncthreads();
    #pragma unroll
    for (int sr = 0; sr < 8; sr++) {
      f32x4 v = *(const f32x4*)((char*)lds + swzb(sr * 4096 + tid * 16));
      v += bv;
      size_t off = ((size_t)(s0 + g * 8 + sr) * 1024 + t0) * 64 + tid * 4;
      __builtin_nontemporal_store(v, (f32x4*)(out + off));
    }
  }
}

extern "C" void kernel_launch(void* const* d_in, const int* in_sizes, int n_in,
                              void* d_out, int out_size, void* d_ws, size_t ws_size,
                              hipStream_t stream) {
  const float* x   = (const float*)d_in[0];
  const float* r   = (const float*)d_in[1];
  const float* Wq  = (const float*)d_in[2];
  const float* bq  = (const float*)d_in[3];
  const float* Wke = (const float*)d_in[4];
  const float* bke = (const float*)d_in[5];
  const float* Wkr = (const float*)d_in[6];
  const float* bkr = (const float*)d_in[7];
  const float* uu  = (const float*)d_in[8];
  const float* vv  = (const float*)d_in[9];
  float* out = (float*)d_out;
  char* ws = (char*)d_ws;

  u16* A2 = (u16*)(ws + 0);                  // 16 MB  [4096][2048] bf16
  u16* QF = (u16*)(ws + 16777216);           // 8 MB   fragment-major Q
  u16* KF = (u16*)(ws + 25165824);           // 8 MB   fragment-major K
  u16* B2 = (u16*)(ws + 33554432);           // 4 MB   [1024][2048]
  u16* Bq = (u16*)(ws + 37748736);           // 2 MB   [1024][1024]
  float* uwke  = (float*)(ws + 39845888);
  float* vwke  = (float*)(ws + 39849984);
  float* wu    = (float*)(ws + 39854080);
  float* wv    = (float*)(ws + 39858176);
  float* biasK = (float*)(ws + 39862272);
  float* cst   = (float*)(ws + 39866368);
  float* biasTB = (float*)(ws + 39866624);   // 16 KB [1024*4]

  k_convert_w<<<1024, 256, 0, stream>>>(Wq, Wke, Wkr, bke, bkr, uu, vv,
                                        Bq, B2, biasK, uwke, vwke);
  k_prep2<<<65, 256, 0, stream>>>(Wke, Wkr, uwke, vwke, bke, bkr, wu, wv, cst);
  k_convert_xr_bias<<<4096, 256, 0, stream>>>(x, r, wu, wv, cst, A2, biasTB);
  k_gemm<<<dim3(8, 32, 2), 256, 0, stream>>>(A2, Bq, B2, bq, biasK, QF, KF);
  k_attn<<<4096, 256, 0, stream>>>(QF, KF, biasTB, out);
}

// Round 5
// 135.639 us; speedup vs baseline: 1.1672x; 1.1672x over previous
//
#include <hip/hip_runtime.h>
#include <hip/hip_bf16.h>
#include <stdint.h>

#define Ssz 1024
#define Bsz 4
#define Csz 1024
#define Hsz 16
#define Msz 4096   // S*B

typedef unsigned short u16;
typedef __attribute__((ext_vector_type(8))) short bf16x8;
typedef __attribute__((ext_vector_type(8))) unsigned short u16x8;
typedef __attribute__((ext_vector_type(4))) float f32x4;
typedef __attribute__((ext_vector_type(4))) unsigned short u16x4;

__device__ __forceinline__ u16 f2bf(float f) {
  union { float f; unsigned u; } x; x.f = f;
  unsigned r = x.u + 0x7fffu + ((x.u >> 16) & 1u);   // RNE
  return (u16)(r >> 16);
}

__device__ __forceinline__ void glds16(const void* g, void* l) {
  __builtin_amdgcn_global_load_lds(
      (__attribute__((address_space(1))) void*)g,
      (__attribute__((address_space(3))) void*)l, 16, 0, 0);
}

// XOR-swizzle a logical LDS byte offset (bank-spread for 256B-strided rows)
__device__ __forceinline__ int swzb(int x) { return x ^ (((x >> 8) & 7) << 4); }

// ---------------- convert weights -> Bq, B2 ; biasK ; uwke/vwke (fused prep1) ----------------
__global__ __launch_bounds__(256) void k_convert_w(
    const float* __restrict__ Wq, const float* __restrict__ Wke, const float* __restrict__ Wkr,
    const float* __restrict__ bke, const float* __restrict__ bkr,
    const float* __restrict__ uu, const float* __restrict__ vv,
    u16* __restrict__ Bq, u16* __restrict__ B2, float* __restrict__ biasK,
    float* __restrict__ uwke, float* __restrict__ vwke) {
  int c = blockIdx.x;
  int tid = threadIdx.x;
  int c4 = tid * 4;
  float4 q = *(const float4*)(Wq + (size_t)c * Csz + c4);
  float4 e = *(const float4*)(Wke + (size_t)c * Csz + c4);
  float4 k = *(const float4*)(Wkr + (size_t)c * Csz + c4);
  u16x4 qo = { f2bf(q.x), f2bf(q.y), f2bf(q.z), f2bf(q.w) };
  u16x4 eo = { f2bf(e.x), f2bf(e.y), f2bf(e.z), f2bf(e.w) };
  u16x4 ko = { f2bf(k.x), f2bf(k.y), f2bf(k.z), f2bf(k.w) };
  *(u16x4*)(Bq + (size_t)c * 1024 + c4) = qo;
  *(u16x4*)(B2 + (size_t)c * 2048 + c4) = eo;
  *(u16x4*)(B2 + (size_t)c * 2048 + 1024 + c4) = ko;
  // fused prep1: uwke[c] = Wke[c]·u + bke[c], vwke[c] = Wkr[c]·v + bkr[c]
  float4 u4 = *(const float4*)(uu + c4);
  float4 v4 = *(const float4*)(vv + c4);
  float se = e.x * u4.x + e.y * u4.y + e.z * u4.z + e.w * u4.w;
  float sk = k.x * v4.x + k.y * v4.y + k.z * v4.z + k.w * v4.w;
  for (int m = 32; m; m >>= 1) { se += __shfl_xor(se, m); sk += __shfl_xor(sk, m); }
  __shared__ float red[2][4];
  if ((tid & 63) == 0) { red[0][tid >> 6] = se; red[1][tid >> 6] = sk; }
  __syncthreads();
  if (tid == 0) {
    uwke[c] = red[0][0] + red[0][1] + red[0][2] + red[0][3] + bke[c];
    vwke[c] = red[1][0] + red[1][1] + red[1][2] + red[1][3] + bkr[c];
    biasK[c] = bke[c] + bkr[c];
  }
}

// ---------------- prep 2: wu = Wke^T uwke ; wv = Wkr^T vwke ; cst ----------------
__global__ __launch_bounds__(256) void k_prep2(
    const float* __restrict__ Wke, const float* __restrict__ Wkr,
    const float* __restrict__ uwke, const float* __restrict__ vwke,
    const float* __restrict__ bke, const float* __restrict__ bkr,
    float* __restrict__ wu, float* __restrict__ wv, float* __restrict__ cst) {
  int bid = blockIdx.x;
  int tid = threadIdx.x;
  if (bid < 64) {
    const float* W = (bid < 32) ? Wke : Wkr;
    const float* sv = (bid < 32) ? uwke : vwke;
    float* o = (bid < 32) ? wu : wv;
    int d = (bid & 31) * 32 + (tid & 31);
    int cpar = tid >> 5;                    // 0..7
    float acc = 0.f;
    #pragma unroll 8
    for (int c = cpar; c < Csz; c += 8) acc += sv[c] * W[(size_t)c * Csz + d];
    __shared__ float red[8][32];
    red[cpar][tid & 31] = acc;
    __syncthreads();
    if (cpar == 0) {
      float s = 0.f;
      #pragma unroll
      for (int i = 0; i < 8; i++) s += red[i][tid & 31];
      o[d] = s;
    }
  } else {
    float s = 0.f;
    for (int i = tid; i < Csz; i += 256) s += uwke[i] * bke[i] + vwke[i] * bkr[i];
    for (int m = 32; m; m >>= 1) s += __shfl_xor(s, m);
    __shared__ float red1[4];
    if ((tid & 63) == 0) red1[tid >> 6] = s;
    __syncthreads();
    if (tid == 0) cst[0] = red1[0] + red1[1] + red1[2] + red1[3];
  }
}

// ---------------- convert x,r -> A2 bf16 [4096][2048] ; fused biasTB ----------------
__global__ __launch_bounds__(256) void k_convert_xr_bias(
    const float* __restrict__ x, const float* __restrict__ r,
    const float* __restrict__ wu, const float* __restrict__ wv,
    const float* __restrict__ cst, u16* __restrict__ A2, float* __restrict__ biasTB) {
  int m = blockIdx.x;
  int tid = threadIdx.x;
  int c4 = tid * 4;
  float4 xv = *(const float4*)(x + (size_t)m * Csz + c4);
  float4 rv = *(const float4*)(r + (size_t)m * Csz + c4);
  u16x4 xo = { f2bf(xv.x), f2bf(xv.y), f2bf(xv.z), f2bf(xv.w) };
  u16x4 ro = { f2bf(rv.x), f2bf(rv.y), f2bf(rv.z), f2bf(rv.w) };
  *(u16x4*)(A2 + (size_t)m * 2048 + c4) = xo;
  *(u16x4*)(A2 + (size_t)m * 2048 + 1024 + c4) = ro;
  // fused bias: biasTB[m] = x[m]·wu + r[m]·wv + cst
  float4 a = *(const float4*)(wu + c4);
  float4 b = *(const float4*)(wv + c4);
  float s = xv.x * a.x + xv.y * a.y + xv.z * a.z + xv.w * a.w
          + rv.x * b.x + rv.y * b.y + rv.z * b.z + rv.w * b.w;
  for (int mm = 32; mm; mm >>= 1) s += __shfl_xor(s, mm);
  __shared__ float red[4];
  if ((tid & 63) == 0) red[tid >> 6] = s;
  __syncthreads();
  if (tid == 0) biasTB[m] = red[0] + red[1] + red[2] + red[3] + cst[0];
}

// ---------------- fused projection GEMMs (z=0: Q, z=1: K) ----------------
// 2-phase double-buffered pipeline; regular stores (QF/KF are re-read by k_attn,
// keep them cacheable — nt here cost ~16us in R4).
__global__ __launch_bounds__(256) void k_gemm(
    const u16* __restrict__ A2, const u16* __restrict__ Bq, const u16* __restrict__ B2,
    const float* __restrict__ bq, const float* __restrict__ biasK,
    u16* __restrict__ QF, u16* __restrict__ KF) {
  __shared__ u16 As[2][4096];
  __shared__ u16 Bs[2][4096];
  __shared__ u16 ep[4][4096];          // 8KB per-wave transpose staging
  const int z = blockIdx.z;
  const u16* A = A2; const int lda = 2048;
  const u16* B = (z == 0) ? Bq : B2;
  const int ldb = (z == 0) ? 1024 : 2048;
  const float* bias = (z == 0) ? bq : biasK;
  u16* OF = (z == 0) ? QF : KF;
  const int NT = ((z == 0) ? 1024 : 2048) >> 5;

  const int tid = threadIdx.x;
  const int bm = blockIdx.y * 128, bn = blockIdx.x * 128;
  const int wave = tid >> 6, lane = tid & 63;
  const int wm = (wave & 1) * 64, wn = (wave >> 1) * 64;
  const int fr = lane & 15, kg = (lane >> 4) * 8;

  const int ch0 = tid, ch1 = 256 + tid;
  const int r0 = ch0 >> 2, c0 = (ch0 & 3) * 8;
  const int r1 = ch1 >> 2, c1 = (ch1 & 3) * 8;
  const u16* a0 = A + (size_t)(bm + r0) * lda + c0;
  const u16* a1 = A + (size_t)(bm + r1) * lda + c1;
  const u16* b0 = B + (size_t)(bn + r0) * ldb + c0;
  const u16* b1 = B + (size_t)(bn + r1) * ldb + c1;

  f32x4 acc[4][4] = {};

  glds16(a0, &As[0][ch0 * 8]);  glds16(a1, &As[0][ch1 * 8]);
  glds16(b0, &Bs[0][ch0 * 8]);  glds16(b1, &Bs[0][ch1 * 8]);
  __syncthreads();

  for (int t = 0; t < NT; t++) {
    const int cur = t & 1;
    if (t + 1 < NT) {
      const int kt = (t + 1) * 32;
      glds16(a0 + kt, &As[cur ^ 1][ch0 * 8]);  glds16(a1 + kt, &As[cur ^ 1][ch1 * 8]);
      glds16(b0 + kt, &Bs[cur ^ 1][ch0 * 8]);  glds16(b1 + kt, &Bs[cur ^ 1][ch1 * 8]);
    }
    bf16x8 af[4], bf[4];
    #pragma unroll
    for (int mi = 0; mi < 4; mi++) af[mi] = *(const bf16x8*)(&As[cur][(wm + mi * 16 + fr) * 32 + kg]);
    #pragma unroll
    for (int ni = 0; ni < 4; ni++) bf[ni] = *(const bf16x8*)(&Bs[cur][(wn + ni * 16 + fr) * 32 + kg]);
    #pragma unroll
    for (int mi = 0; mi < 4; mi++)
      #pragma unroll
      for (int ni = 0; ni < 4; ni++)
        acc[mi][ni] = __builtin_amdgcn_mfma_f32_16x16x32_bf16(af[mi], bf[ni], acc[mi][ni], 0, 0, 0);
    __syncthreads();
  }

  // ---- epilogue: per-wave transpose into fragment layout
  const int hi = lane >> 4;
  const int e8 = fr & 7;
  const int fr3 = fr >> 3;
  float bvn[4];
  #pragma unroll
  for (int ni = 0; ni < 4; ni++) bvn[ni] = bias[bn + wn + ni * 16 + fr];
  #pragma unroll
  for (int ni = 0; ni < 4; ni++) {
    const int kk = ni >> 1;
    const int g = (ni * 2 + fr3) & 3;
    #pragma unroll
    for (int mi = 0; mi < 4; mi++) {
      const int inner = (g * 16 + mi * 4 + hi) * 8 + e8;
      #pragma unroll
      for (int j = 0; j < 4; j++)
        ep[wave][(j * 2 + kk) * 512 + inner] = f2bf(acc[mi][ni][j] + bvn[ni]);
    }
  }
  const int s_tile = (bm >> 6) + (wm >> 6);
  const int nh = (bn + wn) >> 6;
  #pragma unroll
  for (int p = 0; p < 8; p++) {
    const int b2 = p >> 1, kk = p & 1;
    u16x8 v = *(const u16x8*)(&ep[wave][p * 512 + lane * 8]);
    size_t ci = ((size_t)(s_tile * 4 + b2) * 16 + nh) * 2 + kk;
    *(u16x8*)(OF + ci * 512 + lane * 8) = v;
  }
}

// ---------------- attention ----------------
__global__ __launch_bounds__(256, 3) void k_attn(
    const u16* __restrict__ QF, const u16* __restrict__ KF,
    const float* __restrict__ biasTB, float* __restrict__ out) {
  int id = blockIdx.x;                  // 0..4095
  int xcd = id & 7, within = id >> 3;
  int sx = xcd & 3, tx = xcd >> 2;
  int panel = within >> 7;              // 0..3
  int pl = within & 127;
  int s_tile = sx * 16 + (pl >> 3);     // 0..63
  int t_tile = tx * 32 + panel * 8 + (pl & 7);
  int s0 = s_tile * 16, t0 = t_tile * 16;

  int tid = threadIdx.x;
  int wave = tid >> 6, lane = tid & 63; // wave = b
  int fr = lane & 15;

  const u16* qp = QF + (size_t)(s_tile * 4 + wave) * 16384 + lane * 8;
  const u16* kp = KF + (size_t)(t_tile * 4 + wave) * 16384 + lane * 8;

  f32x4 acc[16];
  #pragma unroll
  for (int n = 0; n < 16; n++) acc[n] = (f32x4){0.f, 0.f, 0.f, 0.f};

  #pragma unroll
  for (int n = 0; n < 16; n++) {
    #pragma unroll
    for (int kk = 0; kk < 2; kk++) {
      bf16x8 a  = *(const bf16x8*)(qp + (n * 2 + kk) * 512);
      bf16x8 bb = *(const bf16x8*)(kp + (n * 2 + kk) * 512);
      acc[n] = __builtin_amdgcn_mfma_f32_16x16x32_bf16(a, bb, acc[n], 0, 0, 0);
    }
  }

  __shared__ float lds[8192];
  float bv = biasTB[(t0 + (tid >> 4)) * 4 + ((tid >> 2) & 3)];
  int hi = (lane >> 4) & 1;
  int myg = (lane >> 4) >> 1;

  #pragma unroll
  for (int g = 0; g < 2; g++) {
    __syncthreads();
    if (myg == g) {
      #pragma unroll
      for (int j = 0; j < 4; j++) {
        int lbase = (((hi * 4 + j) * 16 + fr) * 4 + wave) * 64;
        #pragma unroll
        for (int n0 = 0; n0 < 16; n0 += 4) {
          f32x4 v = { acc[n0][j], acc[n0 + 1][j], acc[n0 + 2][j], acc[n0 + 3][j] };
          *(f32x4*)((char*)lds + swzb(lbase + n0 * 4)) = v;
        }
      }
    }
    __syncthreads();
    #pragma unroll
    for (int sr = 0; sr < 8; sr++) {
      f32x4 v = *(const f32x4*)((char*)lds + swzb(sr * 4096 + tid * 16));
      v += bv;
      size_t off = ((size_t)(s0 + g * 8 + sr) * 1024 + t0) * 64 + tid * 4;
      __builtin_nontemporal_store(v, (f32x4*)(out + off));
    }
  }
}

extern "C" void kernel_launch(void* const* d_in, const int* in_sizes, int n_in,
                              void* d_out, int out_size, void* d_ws, size_t ws_size,
                              hipStream_t stream) {
  const float* x   = (const float*)d_in[0];
  const float* r   = (const float*)d_in[1];
  const float* Wq  = (const float*)d_in[2];
  const float* bq  = (const float*)d_in[3];
  const float* Wke = (const float*)d_in[4];
  const float* bke = (const float*)d_in[5];
  const float* Wkr = (const float*)d_in[6];
  const float* bkr = (const float*)d_in[7];
  const float* uu  = (const float*)d_in[8];
  const float* vv  = (const float*)d_in[9];
  float* out = (float*)d_out;
  char* ws = (char*)d_ws;

  u16* A2 = (u16*)(ws + 0);                  // 16 MB  [4096][2048] bf16
  u16* QF = (u16*)(ws + 16777216);           // 8 MB   fragment-major Q
  u16* KF = (u16*)(ws + 25165824);           // 8 MB   fragment-major K
  u16* B2 = (u16*)(ws + 33554432);           // 4 MB   [1024][2048]
  u16* Bq = (u16*)(ws + 37748736);           // 2 MB   [1024][1024]
  float* uwke  = (float*)(ws + 39845888);
  float* vwke  = (float*)(ws + 39849984);
  float* wu    = (float*)(ws + 39854080);
  float* wv    = (float*)(ws + 39858176);
  float* biasK = (float*)(ws + 39862272);
  float* cst   = (float*)(ws + 39866368);
  float* biasTB = (float*)(ws + 39866624);   // 16 KB [1024*4]

  k_convert_w<<<1024, 256, 0, stream>>>(Wq, Wke, Wkr, bke, bkr, uu, vv,
                                        Bq, B2, biasK, uwke, vwke);
  k_prep2<<<65, 256, 0, stream>>>(Wke, Wkr, uwke, vwke, bke, bkr, wu, wv, cst);
  k_convert_xr_bias<<<4096, 256, 0, stream>>>(x, r, wu, wv, cst, A2, biasTB);
  k_gemm<<<dim3(8, 32, 2), 256, 0, stream>>>(A2, Bq, B2, bq, biasK, QF, KF);
  k_attn<<<4096, 256, 0, stream>>>(QF, KF, biasTB, out);
}

// Round 6
// 129.969 us; speedup vs baseline: 1.2181x; 1.0436x over previous
//
#include <hip/hip_runtime.h>
#include <hip/hip_bf16.h>
#include <stdint.h>

#define Ssz 1024
#define Bsz 4
#define Csz 1024
#define Hsz 16
#define Msz 4096   // S*B

typedef unsigned short u16;
typedef __attribute__((ext_vector_type(8))) short bf16x8;
typedef __attribute__((ext_vector_type(8))) unsigned short u16x8;
typedef __attribute__((ext_vector_type(4))) float f32x4;
typedef __attribute__((ext_vector_type(4))) unsigned short u16x4;

__device__ __forceinline__ u16 f2bf(float f) {
  union { float f; unsigned u; } x; x.f = f;
  unsigned r = x.u + 0x7fffu + ((x.u >> 16) & 1u);   // RNE
  return (u16)(r >> 16);
}

__device__ __forceinline__ void glds16(const void* g, void* l) {
  __builtin_amdgcn_global_load_lds(
      (__attribute__((address_space(1))) void*)g,
      (__attribute__((address_space(3))) void*)l, 16, 0, 0);
}

// XOR-swizzle a logical LDS byte offset (bank-spread for 256B-strided rows)
__device__ __forceinline__ int swzb(int x) { return x ^ (((x >> 8) & 7) << 4); }

// ---------------- convert weights -> Bq, B2 ; biasK ; uwke/vwke (fused prep1) ----------------
__global__ __launch_bounds__(256) void k_convert_w(
    const float* __restrict__ Wq, const float* __restrict__ Wke, const float* __restrict__ Wkr,
    const float* __restrict__ bke, const float* __restrict__ bkr,
    const float* __restrict__ uu, const float* __restrict__ vv,
    u16* __restrict__ Bq, u16* __restrict__ B2, float* __restrict__ biasK,
    float* __restrict__ uwke, float* __restrict__ vwke) {
  int c = blockIdx.x;
  int tid = threadIdx.x;
  int c4 = tid * 4;
  float4 q = *(const float4*)(Wq + (size_t)c * Csz + c4);
  float4 e = *(const float4*)(Wke + (size_t)c * Csz + c4);
  float4 k = *(const float4*)(Wkr + (size_t)c * Csz + c4);
  u16x4 qo = { f2bf(q.x), f2bf(q.y), f2bf(q.z), f2bf(q.w) };
  u16x4 eo = { f2bf(e.x), f2bf(e.y), f2bf(e.z), f2bf(e.w) };
  u16x4 ko = { f2bf(k.x), f2bf(k.y), f2bf(k.z), f2bf(k.w) };
  *(u16x4*)(Bq + (size_t)c * 1024 + c4) = qo;
  *(u16x4*)(B2 + (size_t)c * 2048 + c4) = eo;
  *(u16x4*)(B2 + (size_t)c * 2048 + 1024 + c4) = ko;
  // fused prep1: uwke[c] = Wke[c]·u + bke[c], vwke[c] = Wkr[c]·v + bkr[c]
  float4 u4 = *(const float4*)(uu + c4);
  float4 v4 = *(const float4*)(vv + c4);
  float se = e.x * u4.x + e.y * u4.y + e.z * u4.z + e.w * u4.w;
  float sk = k.x * v4.x + k.y * v4.y + k.z * v4.z + k.w * v4.w;
  for (int m = 32; m; m >>= 1) { se += __shfl_xor(se, m); sk += __shfl_xor(sk, m); }
  __shared__ float red[2][4];
  if ((tid & 63) == 0) { red[0][tid >> 6] = se; red[1][tid >> 6] = sk; }
  __syncthreads();
  if (tid == 0) {
    uwke[c] = red[0][0] + red[0][1] + red[0][2] + red[0][3] + bke[c];
    vwke[c] = red[1][0] + red[1][1] + red[1][2] + red[1][3] + bkr[c];
    biasK[c] = bke[c] + bkr[c];
  }
}

// ---------------- prep 2: wu = Wke^T uwke ; wv = Wkr^T vwke ; cst ----------------
__global__ __launch_bounds__(256) void k_prep2(
    const float* __restrict__ Wke, const float* __restrict__ Wkr,
    const float* __restrict__ uwke, const float* __restrict__ vwke,
    const float* __restrict__ bke, const float* __restrict__ bkr,
    float* __restrict__ wu, float* __restrict__ wv, float* __restrict__ cst) {
  int bid = blockIdx.x;
  int tid = threadIdx.x;
  if (bid < 64) {
    const float* W = (bid < 32) ? Wke : Wkr;
    const float* sv = (bid < 32) ? uwke : vwke;
    float* o = (bid < 32) ? wu : wv;
    int d = (bid & 31) * 32 + (tid & 31);
    int cpar = tid >> 5;                    // 0..7
    float acc = 0.f;
    #pragma unroll 8
    for (int c = cpar; c < Csz; c += 8) acc += sv[c] * W[(size_t)c * Csz + d];
    __shared__ float red[8][32];
    red[cpar][tid & 31] = acc;
    __syncthreads();
    if (cpar == 0) {
      float s = 0.f;
      #pragma unroll
      for (int i = 0; i < 8; i++) s += red[i][tid & 31];
      o[d] = s;
    }
  } else {
    float s = 0.f;
    for (int i = tid; i < Csz; i += 256) s += uwke[i] * bke[i] + vwke[i] * bkr[i];
    for (int m = 32; m; m >>= 1) s += __shfl_xor(s, m);
    __shared__ float red1[4];
    if ((tid & 63) == 0) red1[tid >> 6] = s;
    __syncthreads();
    if (tid == 0) cst[0] = red1[0] + red1[1] + red1[2] + red1[3];
  }
}

// ---------------- convert x,r -> A2 bf16 [4096][2048] ; fused biasTB ----------------
__global__ __launch_bounds__(256) void k_convert_xr_bias(
    const float* __restrict__ x, const float* __restrict__ r,
    const float* __restrict__ wu, const float* __restrict__ wv,
    const float* __restrict__ cst, u16* __restrict__ A2, float* __restrict__ biasTB) {
  int m = blockIdx.x;
  int tid = threadIdx.x;
  int c4 = tid * 4;
  float4 xv = *(const float4*)(x + (size_t)m * Csz + c4);
  float4 rv = *(const float4*)(r + (size_t)m * Csz + c4);
  u16x4 xo = { f2bf(xv.x), f2bf(xv.y), f2bf(xv.z), f2bf(xv.w) };
  u16x4 ro = { f2bf(rv.x), f2bf(rv.y), f2bf(rv.z), f2bf(rv.w) };
  *(u16x4*)(A2 + (size_t)m * 2048 + c4) = xo;
  *(u16x4*)(A2 + (size_t)m * 2048 + 1024 + c4) = ro;
  // fused bias: biasTB[m] = x[m]·wu + r[m]·wv + cst
  float4 a = *(const float4*)(wu + c4);
  float4 b = *(const float4*)(wv + c4);
  float s = xv.x * a.x + xv.y * a.y + xv.z * a.z + xv.w * a.w
          + rv.x * b.x + rv.y * b.y + rv.z * b.z + rv.w * b.w;
  for (int mm = 32; mm; mm >>= 1) s += __shfl_xor(s, mm);
  __shared__ float red[4];
  if ((tid & 63) == 0) red[tid >> 6] = s;
  __syncthreads();
  if (tid == 0) biasTB[m] = red[0] + red[1] + red[2] + red[3] + cst[0];
}

// ---------------- fused projection GEMMs (z=0: Q, z=1: K) ----------------
// 2-phase double-buffered pipeline. Epilogue transpose staging OVERLAYS the
// (dead-after-loop) As/Bs buffers: LDS = 32 KB exactly -> 4 blocks/CU.
__global__ __launch_bounds__(256, 4) void k_gemm(
    const u16* __restrict__ A2, const u16* __restrict__ Bq, const u16* __restrict__ B2,
    const float* __restrict__ bq, const float* __restrict__ biasK,
    u16* __restrict__ QF, u16* __restrict__ KF) {
  __shared__ char smem[32768];
  u16 (*As)[4096] = (u16(*)[4096])smem;            // 2 x 8 KB
  u16 (*Bs)[4096] = (u16(*)[4096])(smem + 16384);  // 2 x 8 KB
  u16* ep = (u16*)smem;                            // epilogue overlay: wave w -> ep + w*4096

  const int z = blockIdx.z;
  const u16* A = A2; const int lda = 2048;
  const u16* B = (z == 0) ? Bq : B2;
  const int ldb = (z == 0) ? 1024 : 2048;
  const float* bias = (z == 0) ? bq : biasK;
  u16* OF = (z == 0) ? QF : KF;
  const int NT = ((z == 0) ? 1024 : 2048) >> 5;

  const int tid = threadIdx.x;
  const int bm = blockIdx.y * 128, bn = blockIdx.x * 128;
  const int wave = tid >> 6, lane = tid & 63;
  const int wm = (wave & 1) * 64, wn = (wave >> 1) * 64;
  const int fr = lane & 15, kg = (lane >> 4) * 8;

  const int ch0 = tid, ch1 = 256 + tid;
  const int r0 = ch0 >> 2, c0 = (ch0 & 3) * 8;
  const int r1 = ch1 >> 2, c1 = (ch1 & 3) * 8;
  const u16* a0 = A + (size_t)(bm + r0) * lda + c0;
  const u16* a1 = A + (size_t)(bm + r1) * lda + c1;
  const u16* b0 = B + (size_t)(bn + r0) * ldb + c0;
  const u16* b1 = B + (size_t)(bn + r1) * ldb + c1;

  f32x4 acc[4][4] = {};

  glds16(a0, &As[0][ch0 * 8]);  glds16(a1, &As[0][ch1 * 8]);
  glds16(b0, &Bs[0][ch0 * 8]);  glds16(b1, &Bs[0][ch1 * 8]);
  __syncthreads();

  for (int t = 0; t < NT; t++) {
    const int cur = t & 1;
    if (t + 1 < NT) {
      const int kt = (t + 1) * 32;
      glds16(a0 + kt, &As[cur ^ 1][ch0 * 8]);  glds16(a1 + kt, &As[cur ^ 1][ch1 * 8]);
      glds16(b0 + kt, &Bs[cur ^ 1][ch0 * 8]);  glds16(b1 + kt, &Bs[cur ^ 1][ch1 * 8]);
    }
    bf16x8 af[4], bf[4];
    #pragma unroll
    for (int mi = 0; mi < 4; mi++) af[mi] = *(const bf16x8*)(&As[cur][(wm + mi * 16 + fr) * 32 + kg]);
    #pragma unroll
    for (int ni = 0; ni < 4; ni++) bf[ni] = *(const bf16x8*)(&Bs[cur][(wn + ni * 16 + fr) * 32 + kg]);
    #pragma unroll
    for (int mi = 0; mi < 4; mi++)
      #pragma unroll
      for (int ni = 0; ni < 4; ni++)
        acc[mi][ni] = __builtin_amdgcn_mfma_f32_16x16x32_bf16(af[mi], bf[ni], acc[mi][ni], 0, 0, 0);
    __syncthreads();
  }
  // K-loop done; final barrier above makes As/Bs dead -> safe to overlay ep.

  // ---- epilogue: per-wave transpose into fragment layout
  const int hi = lane >> 4;
  const int e8 = fr & 7;
  const int fr3 = fr >> 3;
  u16* epw = ep + wave * 4096;           // 8 KB per wave, private
  float bvn[4];
  #pragma unroll
  for (int ni = 0; ni < 4; ni++) bvn[ni] = bias[bn + wn + ni * 16 + fr];
  #pragma unroll
  for (int ni = 0; ni < 4; ni++) {
    const int kk = ni >> 1;
    const int g = (ni * 2 + fr3) & 3;
    #pragma unroll
    for (int mi = 0; mi < 4; mi++) {
      const int inner = (g * 16 + mi * 4 + hi) * 8 + e8;
      #pragma unroll
      for (int j = 0; j < 4; j++)
        epw[(j * 2 + kk) * 512 + inner] = f2bf(acc[mi][ni][j] + bvn[ni]);
    }
  }
  const int s_tile = (bm >> 6) + (wm >> 6);
  const int nh = (bn + wn) >> 6;
  #pragma unroll
  for (int p = 0; p < 8; p++) {
    const int b2 = p >> 1, kk = p & 1;
    u16x8 v = *(const u16x8*)(&epw[p * 512 + lane * 8]);
    size_t ci = ((size_t)(s_tile * 4 + b2) * 16 + nh) * 2 + kk;
    *(u16x8*)(OF + ci * 512 + lane * 8) = v;
  }
}

// ---------------- attention ----------------
__global__ __launch_bounds__(256, 3) void k_attn(
    const u16* __restrict__ QF, const u16* __restrict__ KF,
    const float* __restrict__ biasTB, float* __restrict__ out) {
  int id = blockIdx.x;                  // 0..4095
  int xcd = id & 7, within = id >> 3;
  int sx = xcd & 3, tx = xcd >> 2;
  int panel = within >> 7;              // 0..3
  int pl = within & 127;
  int s_tile = sx * 16 + (pl >> 3);     // 0..63
  int t_tile = tx * 32 + panel * 8 + (pl & 7);
  int s0 = s_tile * 16, t0 = t_tile * 16;

  int tid = threadIdx.x;
  int wave = tid >> 6, lane = tid & 63; // wave = b
  int fr = lane & 15;

  const u16* qp = QF + (size_t)(s_tile * 4 + wave) * 16384 + lane * 8;
  const u16* kp = KF + (size_t)(t_tile * 4 + wave) * 16384 + lane * 8;

  f32x4 acc[16];
  #pragma unroll
  for (int n = 0; n < 16; n++) acc[n] = (f32x4){0.f, 0.f, 0.f, 0.f};

  #pragma unroll
  for (int n = 0; n < 16; n++) {
    #pragma unroll
    for (int kk = 0; kk < 2; kk++) {
      bf16x8 a  = *(const bf16x8*)(qp + (n * 2 + kk) * 512);
      bf16x8 bb = *(const bf16x8*)(kp + (n * 2 + kk) * 512);
      acc[n] = __builtin_amdgcn_mfma_f32_16x16x32_bf16(a, bb, acc[n], 0, 0, 0);
    }
  }

  __shared__ float lds[8192];
  float bv = biasTB[(t0 + (tid >> 4)) * 4 + ((tid >> 2) & 3)];
  int hi = (lane >> 4) & 1;
  int myg = (lane >> 4) >> 1;

  #pragma unroll
  for (int g = 0; g < 2; g++) {
    __syncthreads();
    if (myg == g) {
      #pragma unroll
      for (int j = 0; j < 4; j++) {
        int lbase = (((hi * 4 + j) * 16 + fr) * 4 + wave) * 64;
        #pragma unroll
        for (int n0 = 0; n0 < 16; n0 += 4) {
          f32x4 v = { acc[n0][j], acc[n0 + 1][j], acc[n0 + 2][j], acc[n0 + 3][j] };
          *(f32x4*)((char*)lds + swzb(lbase + n0 * 4)) = v;
        }
      }
    }
    __syncthreads();
    #pragma unroll
    for (int sr = 0; sr < 8; sr++) {
      f32x4 v = *(const f32x4*)((char*)lds + swzb(sr * 4096 + tid * 16));
      v += bv;
      size_t off = ((size_t)(s0 + g * 8 + sr) * 1024 + t0) * 64 + tid * 4;
      __builtin_nontemporal_store(v, (f32x4*)(out + off));
    }
  }
}

extern "C" void kernel_launch(void* const* d_in, const int* in_sizes, int n_in,
                              void* d_out, int out_size, void* d_ws, size_t ws_size,
                              hipStream_t stream) {
  const float* x   = (const float*)d_in[0];
  const float* r   = (const float*)d_in[1];
  const float* Wq  = (const float*)d_in[2];
  const float* bq  = (const float*)d_in[3];
  const float* Wke = (const float*)d_in[4];
  const float* bke = (const float*)d_in[5];
  const float* Wkr = (const float*)d_in[6];
  const float* bkr = (const float*)d_in[7];
  const float* uu  = (const float*)d_in[8];
  const float* vv  = (const float*)d_in[9];
  float* out = (float*)d_out;
  char* ws = (char*)d_ws;

  u16* A2 = (u16*)(ws + 0);                  // 16 MB  [4096][2048] bf16
  u16* QF = (u16*)(ws + 16777216);           // 8 MB   fragment-major Q
  u16* KF = (u16*)(ws + 25165824);           // 8 MB   fragment-major K
  u16* B2 = (u16*)(ws + 33554432);           // 4 MB   [1024][2048]
  u16* Bq = (u16*)(ws + 37748736);           // 2 MB   [1024][1024]
  float* uwke  = (float*)(ws + 39845888);
  float* vwke  = (float*)(ws + 39849984);
  float* wu    = (float*)(ws + 39854080);
  float* wv    = (float*)(ws + 39858176);
  float* biasK = (float*)(ws + 39862272);
  float* cst   = (float*)(ws + 39866368);
  float* biasTB = (float*)(ws + 39866624);   // 16 KB [1024*4]

  k_convert_w<<<1024, 256, 0, stream>>>(Wq, Wke, Wkr, bke, bkr, uu, vv,
                                        Bq, B2, biasK, uwke, vwke);
  k_prep2<<<65, 256, 0, stream>>>(Wke, Wkr, uwke, vwke, bke, bkr, wu, wv, cst);
  k_convert_xr_bias<<<4096, 256, 0, stream>>>(x, r, wu, wv, cst, A2, biasTB);
  k_gemm<<<dim3(8, 32, 2), 256, 0, stream>>>(A2, Bq, B2, bq, biasK, QF, KF);
  k_attn<<<4096, 256, 0, stream>>>(QF, KF, biasTB, out);
}

// Round 9
// 126.865 us; speedup vs baseline: 1.2479x; 1.0245x over previous
//
#include <hip/hip_runtime.h>
#include <hip/hip_bf16.h>
#include <stdint.h>

#define Ssz 1024
#define Bsz 4
#define Csz 1024
#define Hsz 16
#define Msz 4096   // S*B

typedef unsigned short u16;
typedef __attribute__((ext_vector_type(8))) short bf16x8;
typedef __attribute__((ext_vector_type(8))) unsigned short u16x8;
typedef __attribute__((ext_vector_type(4))) float f32x4;
typedef __attribute__((ext_vector_type(4))) unsigned short u16x4;

__device__ __forceinline__ u16 f2bf(float f) {
  union { float f; unsigned u; } x; x.f = f;
  unsigned r = x.u + 0x7fffu + ((x.u >> 16) & 1u);   // RNE
  return (u16)(r >> 16);
}

__device__ __forceinline__ void glds16(const void* g, void* l) {
  __builtin_amdgcn_global_load_lds(
      (__attribute__((address_space(1))) void*)g,
      (__attribute__((address_space(3))) void*)l, 16, 0, 0);
}

// XOR-swizzle a logical LDS byte offset (bank-spread for 256B-strided rows)
__device__ __forceinline__ int swzb(int x) { return x ^ (((x >> 8) & 7) << 4); }

// ---------------- convert weights -> Bq, B2 ; biasK ; uwke/vwke (fused prep1) ----------------
__global__ __launch_bounds__(256) void k_convert_w(
    const float* __restrict__ Wq, const float* __restrict__ Wke, const float* __restrict__ Wkr,
    const float* __restrict__ bke, const float* __restrict__ bkr,
    const float* __restrict__ uu, const float* __restrict__ vv,
    u16* __restrict__ Bq, u16* __restrict__ B2, float* __restrict__ biasK,
    float* __restrict__ uwke, float* __restrict__ vwke) {
  int c = blockIdx.x;
  int tid = threadIdx.x;
  int c4 = tid * 4;
  float4 q = *(const float4*)(Wq + (size_t)c * Csz + c4);
  float4 e = *(const float4*)(Wke + (size_t)c * Csz + c4);
  float4 k = *(const float4*)(Wkr + (size_t)c * Csz + c4);
  u16x4 qo = { f2bf(q.x), f2bf(q.y), f2bf(q.z), f2bf(q.w) };
  u16x4 eo = { f2bf(e.x), f2bf(e.y), f2bf(e.z), f2bf(e.w) };
  u16x4 ko = { f2bf(k.x), f2bf(k.y), f2bf(k.z), f2bf(k.w) };
  *(u16x4*)(Bq + (size_t)c * 1024 + c4) = qo;
  *(u16x4*)(B2 + (size_t)c * 2048 + c4) = eo;
  *(u16x4*)(B2 + (size_t)c * 2048 + 1024 + c4) = ko;
  // fused prep1: uwke[c] = Wke[c]·u + bke[c], vwke[c] = Wkr[c]·v + bkr[c]
  float4 u4 = *(const float4*)(uu + c4);
  float4 v4 = *(const float4*)(vv + c4);
  float se = e.x * u4.x + e.y * u4.y + e.z * u4.z + e.w * u4.w;
  float sk = k.x * v4.x + k.y * v4.y + k.z * v4.z + k.w * v4.w;
  for (int m = 32; m; m >>= 1) { se += __shfl_xor(se, m); sk += __shfl_xor(sk, m); }
  __shared__ float red[2][4];
  if ((tid & 63) == 0) { red[0][tid >> 6] = se; red[1][tid >> 6] = sk; }
  __syncthreads();
  if (tid == 0) {
    uwke[c] = red[0][0] + red[0][1] + red[0][2] + red[0][3] + bke[c];
    vwke[c] = red[1][0] + red[1][1] + red[1][2] + red[1][3] + bkr[c];
    biasK[c] = bke[c] + bkr[c];
  }
}

// ---------------- prep 2: wu = Wke^T uwke ; wv = Wkr^T vwke ; cst ----------------
__global__ __launch_bounds__(256) void k_prep2(
    const float* __restrict__ Wke, const float* __restrict__ Wkr,
    const float* __restrict__ uwke, const float* __restrict__ vwke,
    const float* __restrict__ bke, const float* __restrict__ bkr,
    float* __restrict__ wu, float* __restrict__ wv, float* __restrict__ cst) {
  int bid = blockIdx.x;
  int tid = threadIdx.x;
  if (bid < 64) {
    const float* W = (bid < 32) ? Wke : Wkr;
    const float* sv = (bid < 32) ? uwke : vwke;
    float* o = (bid < 32) ? wu : wv;
    int d = (bid & 31) * 32 + (tid & 31);
    int cpar = tid >> 5;                    // 0..7
    float acc = 0.f;
    #pragma unroll 8
    for (int c = cpar; c < Csz; c += 8) acc += sv[c] * W[(size_t)c * Csz + d];
    __shared__ float red[8][32];
    red[cpar][tid & 31] = acc;
    __syncthreads();
    if (cpar == 0) {
      float s = 0.f;
      #pragma unroll
      for (int i = 0; i < 8; i++) s += red[i][tid & 31];
      o[d] = s;
    }
  } else {
    float s = 0.f;
    for (int i = tid; i < Csz; i += 256) s += uwke[i] * bke[i] + vwke[i] * bkr[i];
    for (int m = 32; m; m >>= 1) s += __shfl_xor(s, m);
    __shared__ float red1[4];
    if ((tid & 63) == 0) red1[tid >> 6] = s;
    __syncthreads();
    if (tid == 0) cst[0] = red1[0] + red1[1] + red1[2] + red1[3];
  }
}

// ---------------- convert x,r -> A2 bf16 [4096][2048] ; fused biasTB ----------------
__global__ __launch_bounds__(256) void k_convert_xr_bias(
    const float* __restrict__ x, const float* __restrict__ r,
    const float* __restrict__ wu, const float* __restrict__ wv,
    const float* __restrict__ cst, u16* __restrict__ A2, float* __restrict__ biasTB) {
  int m = blockIdx.x;
  int tid = threadIdx.x;
  int c4 = tid * 4;
  float4 xv = *(const float4*)(x + (size_t)m * Csz + c4);
  float4 rv = *(const float4*)(r + (size_t)m * Csz + c4);
  u16x4 xo = { f2bf(xv.x), f2bf(xv.y), f2bf(xv.z), f2bf(xv.w) };
  u16x4 ro = { f2bf(rv.x), f2bf(rv.y), f2bf(rv.z), f2bf(rv.w) };
  *(u16x4*)(A2 + (size_t)m * 2048 + c4) = xo;
  *(u16x4*)(A2 + (size_t)m * 2048 + 1024 + c4) = ro;
  // fused bias: biasTB[m] = x[m]·wu + r[m]·wv + cst
  float4 a = *(const float4*)(wu + c4);
  float4 b = *(const float4*)(wv + c4);
  float s = xv.x * a.x + xv.y * a.y + xv.z * a.z + xv.w * a.w
          + rv.x * b.x + rv.y * b.y + rv.z * b.z + rv.w * b.w;
  for (int mm = 32; mm; mm >>= 1) s += __shfl_xor(s, mm);
  __shared__ float red[4];
  if ((tid & 63) == 0) red[tid >> 6] = s;
  __syncthreads();
  if (tid == 0) biasTB[m] = red[0] + red[1] + red[2] + red[3] + cst[0];
}

// ---------------- fused projection GEMMs (z=0: Q, z=1: K) ----------------
// Triple-buffered pipeline with counted vmcnt (T3+T4): prefetch 2 tiles ahead,
// raw s_barrier + s_waitcnt vmcnt(4). FINAL iteration must drain vmcnt(0):
// only 4 loads (the needed tile) are outstanding there, so vmcnt(4) would
// pass without waiting — that was R8's race.
__global__ __launch_bounds__(256, 3) void k_gemm(
    const u16* __restrict__ A2, const u16* __restrict__ Bq, const u16* __restrict__ B2,
    const float* __restrict__ bq, const float* __restrict__ biasK,
    u16* __restrict__ QF, u16* __restrict__ KF) {
  __shared__ u16 smem[24576];                 // 48 KB: 3 slots x (8KB A + 8KB B)
  // slot s: A at smem + s*8192, B at smem + s*8192 + 4096   (u16 units)

  const int z = blockIdx.z;
  const u16* A = A2; const int lda = 2048;
  const u16* B = (z == 0) ? Bq : B2;
  const int ldb = (z == 0) ? 1024 : 2048;
  const float* bias = (z == 0) ? bq : biasK;
  u16* OF = (z == 0) ? QF : KF;
  const int NT = ((z == 0) ? 1024 : 2048) >> 5;

  const int tid = threadIdx.x;
  const int bm = blockIdx.y * 128, bn = blockIdx.x * 128;
  const int wave = tid >> 6, lane = tid & 63;
  const int wm = (wave & 1) * 64, wn = (wave >> 1) * 64;
  const int fr = lane & 15, kg = (lane >> 4) * 8;

  const int ch0 = tid, ch1 = 256 + tid;
  const int r0 = ch0 >> 2, c0 = (ch0 & 3) * 8;
  const int r1 = ch1 >> 2, c1 = (ch1 & 3) * 8;
  const u16* a0 = A + (size_t)(bm + r0) * lda + c0;
  const u16* a1 = A + (size_t)(bm + r1) * lda + c1;
  const u16* b0 = B + (size_t)(bn + r0) * ldb + c0;
  const u16* b1 = B + (size_t)(bn + r1) * ldb + c1;

  f32x4 acc[4][4] = {};

  // prologue: stage tiles 0 and 1 into slots 0 and 1
  glds16(a0, smem + ch0 * 8);           glds16(a1, smem + ch1 * 8);
  glds16(b0, smem + 4096 + ch0 * 8);    glds16(b1, smem + 4096 + ch1 * 8);
  glds16(a0 + 32, smem + 8192 + ch0 * 8);        glds16(a1 + 32, smem + 8192 + ch1 * 8);
  glds16(b0 + 32, smem + 8192 + 4096 + ch0 * 8); glds16(b1 + 32, smem + 8192 + 4096 + ch1 * 8);

  int cur = 0;
  for (int t = 0; t < NT; t++) {
    // wait for tile t's loads: they are the 4 oldest of 8 outstanding
    // (normal case) -> vmcnt(4); at t==NT-1 they are the ONLY 4 -> vmcnt(0).
    if (t == NT - 1) {
      asm volatile("s_waitcnt vmcnt(0)" ::: "memory");
    } else {
      asm volatile("s_waitcnt vmcnt(4)" ::: "memory");
    }
    __builtin_amdgcn_s_barrier();
    asm volatile("" ::: "memory");
    if (t + 2 < NT) {                  // prefetch tile t+2 into slot of dead tile t-1
      const int nxt = cur >= 1 ? cur - 1 : 2;   // (cur+2)%3
      u16* an = smem + nxt * 8192;
      u16* bn_ = an + 4096;
      const int kt = (t + 2) * 32;
      glds16(a0 + kt, an + ch0 * 8);   glds16(a1 + kt, an + ch1 * 8);
      glds16(b0 + kt, bn_ + ch0 * 8);  glds16(b1 + kt, bn_ + ch1 * 8);
    }
    const u16* ac = smem + cur * 8192;
    const u16* bc = ac + 4096;
    bf16x8 af[4], bf[4];
    #pragma unroll
    for (int mi = 0; mi < 4; mi++) af[mi] = *(const bf16x8*)(ac + (wm + mi * 16 + fr) * 32 + kg);
    #pragma unroll
    for (int ni = 0; ni < 4; ni++) bf[ni] = *(const bf16x8*)(bc + (wn + ni * 16 + fr) * 32 + kg);
    #pragma unroll
    for (int mi = 0; mi < 4; mi++)
      #pragma unroll
      for (int ni = 0; ni < 4; ni++)
        acc[mi][ni] = __builtin_amdgcn_mfma_f32_16x16x32_bf16(af[mi], bf[ni], acc[mi][ni], 0, 0, 0);
    cur = cur < 2 ? cur + 1 : 0;
  }
  // all prefetches drained (last iteration waited vmcnt(0)); barrier before overlay
  __syncthreads();

  // ---- epilogue: per-wave transpose into fragment layout
  const int hi = lane >> 4;
  const int e8 = fr & 7;
  const int fr3 = fr >> 3;
  u16* epw = smem + wave * 4096;         // 8 KB per wave, private
  float bvn[4];
  #pragma unroll
  for (int ni = 0; ni < 4; ni++) bvn[ni] = bias[bn + wn + ni * 16 + fr];
  #pragma unroll
  for (int ni = 0; ni < 4; ni++) {
    const int kk = ni >> 1;
    const int g = (ni * 2 + fr3) & 3;
    #pragma unroll
    for (int mi = 0; mi < 4; mi++) {
      const int inner = (g * 16 + mi * 4 + hi) * 8 + e8;
      #pragma unroll
      for (int j = 0; j < 4; j++)
        epw[(j * 2 + kk) * 512 + inner] = f2bf(acc[mi][ni][j] + bvn[ni]);
    }
  }
  const int s_tile = (bm >> 6) + (wm >> 6);
  const int nh = (bn + wn) >> 6;
  #pragma unroll
  for (int p = 0; p < 8; p++) {
    const int b2 = p >> 1, kk = p & 1;
    u16x8 v = *(const u16x8*)(&epw[p * 512 + lane * 8]);
    size_t ci = ((size_t)(s_tile * 4 + b2) * 16 + nh) * 2 + kk;
    *(u16x8*)(OF + ci * 512 + lane * 8) = v;
  }
}

// ---------------- attention ----------------
__global__ __launch_bounds__(256, 3) void k_attn(
    const u16* __restrict__ QF, const u16* __restrict__ KF,
    const float* __restrict__ biasTB, float* __restrict__ out) {
  int id = blockIdx.x;                  // 0..4095
  int xcd = id & 7, within = id >> 3;
  int sx = xcd & 3, tx = xcd >> 2;
  int panel = within >> 7;              // 0..3
  int pl = within & 127;
  int s_tile = sx * 16 + (pl >> 3);     // 0..63
  int t_tile = tx * 32 + panel * 8 + (pl & 7);
  int s0 = s_tile * 16, t0 = t_tile * 16;

  int tid = threadIdx.x;
  int wave = tid >> 6, lane = tid & 63; // wave = b
  int fr = lane & 15;

  const u16* qp = QF + (size_t)(s_tile * 4 + wave) * 16384 + lane * 8;
  const u16* kp = KF + (size_t)(t_tile * 4 + wave) * 16384 + lane * 8;

  f32x4 acc[16];
  #pragma unroll
  for (int n = 0; n < 16; n++) acc[n] = (f32x4){0.f, 0.f, 0.f, 0.f};

  #pragma unroll
  for (int n = 0; n < 16; n++) {
    #pragma unroll
    for (int kk = 0; kk < 2; kk++) {
      bf16x8 a  = *(const bf16x8*)(qp + (n * 2 + kk) * 512);
      bf16x8 bb = *(const bf16x8*)(kp + (n * 2 + kk) * 512);
      acc[n] = __builtin_amdgcn_mfma_f32_16x16x32_bf16(a, bb, acc[n], 0, 0, 0);
    }
  }

  __shared__ float lds[8192];
  float bv = biasTB[(t0 + (tid >> 4)) * 4 + ((tid >> 2) & 3)];
  int hi = (lane >> 4) & 1;
  int myg = (lane >> 4) >> 1;

  #pragma unroll
  for (int g = 0; g < 2; g++) {
    __syncthreads();
    if (myg == g) {
      #pragma unroll
      for (int j = 0; j < 4; j++) {
        int lbase = (((hi * 4 + j) * 16 + fr) * 4 + wave) * 64;
        #pragma unroll
        for (int n0 = 0; n0 < 16; n0 += 4) {
          f32x4 v = { acc[n0][j], acc[n0 + 1][j], acc[n0 + 2][j], acc[n0 + 3][j] };
          *(f32x4*)((char*)lds + swzb(lbase + n0 * 4)) = v;
        }
      }
    }
    __syncthreads();
    #pragma unroll
    for (int sr = 0; sr < 8; sr++) {
      f32x4 v = *(const f32x4*)((char*)lds + swzb(sr * 4096 + tid * 16));
      v += bv;
      size_t off = ((size_t)(s0 + g * 8 + sr) * 1024 + t0) * 64 + tid * 4;
      __builtin_nontemporal_store(v, (f32x4*)(out + off));
    }
  }
}

extern "C" void kernel_launch(void* const* d_in, const int* in_sizes, int n_in,
                              void* d_out, int out_size, void* d_ws, size_t ws_size,
                              hipStream_t stream) {
  const float* x   = (const float*)d_in[0];
  const float* r   = (const float*)d_in[1];
  const float* Wq  = (const float*)d_in[2];
  const float* bq  = (const float*)d_in[3];
  const float* Wke = (const float*)d_in[4];
  const float* bke = (const float*)d_in[5];
  const float* Wkr = (const float*)d_in[6];
  const float* bkr = (const float*)d_in[7];
  const float* uu  = (const float*)d_in[8];
  const float* vv  = (const float*)d_in[9];
  float* out = (float*)d_out;
  char* ws = (char*)d_ws;

  u16* A2 = (u16*)(ws + 0);                  // 16 MB  [4096][2048] bf16
  u16* QF = (u16*)(ws + 16777216);           // 8 MB   fragment-major Q
  u16* KF = (u16*)(ws + 25165824);           // 8 MB   fragment-major K
  u16* B2 = (u16*)(ws + 33554432);           // 4 MB   [1024][2048]
  u16* Bq = (u16*)(ws + 37748736);           // 2 MB   [1024][1024]
  float* uwke  = (float*)(ws + 39845888);
  float* vwke  = (float*)(ws + 39849984);
  float* wu    = (float*)(ws + 39854080);
  float* wv    = (float*)(ws + 39858176);
  float* biasK = (float*)(ws + 39862272);
  float* cst   = (float*)(ws + 39866368);
  float* biasTB = (float*)(ws + 39866624);   // 16 KB [1024*4]

  k_convert_w<<<1024, 256, 0, stream>>>(Wq, Wke, Wkr, bke, bkr, uu, vv,
                                        Bq, B2, biasK, uwke, vwke);
  k_prep2<<<65, 256, 0, stream>>>(Wke, Wkr, uwke, vwke, bke, bkr, wu, wv, cst);
  k_convert_xr_bias<<<4096, 256, 0, stream>>>(x, r, wu, wv, cst, A2, biasTB);
  k_gemm<<<dim3(8, 32, 2), 256, 0, stream>>>(A2, Bq, B2, bq, biasK, QF, KF);
  k_attn<<<4096, 256, 0, stream>>>(QF, KF, biasTB, out);
}